// Round 4
// baseline (271.556 us; speedup 1.0000x reference)
//
#include <hip/hip_runtime.h>
#include <hip/hip_bf16.h>

// Problem constants (match reference)
constexpr int NE  = 8;     // experts
constexpr int T   = 2048;  // tokens
constexpr int IN  = 2048;  // reduction dim
constexpr int OUT = 2048;  // output dim
constexpr int GS  = 64;    // quant group size
constexpr int G   = IN / GS;

// Weight-stationary tiling: block owns (e, n-tile of 64, k-chunk of 512).
// B dequanted ONCE into LDS; token loop has no barriers at all.
constexpr int BN = 64;
constexpr int KC = 512;           // k-chunk; KSPLIT = IN/KC = 4
constexpr int KSPLIT = IN / KC;
constexpr int LDB = KC + 8;       // dword-stride 260 % 32 == 4 -> even bank spread

using short8  = __attribute__((ext_vector_type(8))) short;
using floatx4 = __attribute__((ext_vector_type(4))) float;

// x fp32 -> bf16 pre-pass (A operand; 16.8MB read / 8.4MB write)
__global__ __launch_bounds__(256)
void cvt_x_bf16(const float* __restrict__ x, __hip_bfloat16* __restrict__ xb) {
    const int i = (blockIdx.x * 256 + threadIdx.x) * 4;
    const float4 v = *(const float4*)(x + i);
    union { unsigned long long u; __hip_bfloat162 h2[2]; } p;
    p.h2[0] = __float22bfloat162_rn(float2{v.x, v.y});
    p.h2[1] = __float22bfloat162_rn(float2{v.z, v.w});
    *(unsigned long long*)(xb + i) = p.u;
}

__global__ __launch_bounds__(256, 2)
void hqq_grouped_gemm(const __hip_bfloat16* __restrict__ xb,
                      const int*   __restrict__ qw,
                      const float* __restrict__ snz,   // [E][G][OUT][2]
                      const int*   __restrict__ tpe,   // [E]
                      float* __restrict__ out) {
    const int tid = threadIdx.x;
    const int e   = blockIdx.z;
    const int kc  = blockIdx.y * KC;
    const int n0  = blockIdx.x * BN;

    // expert row bounds (wave-uniform, L2-hot)
    int b0 = 0;
    for (int i = 0; i < NE; ++i) {
        int c = tpe[i];
        if (i < e) b0 += c;
    }
    const int b1 = b0 + tpe[e];
    const int nrows = b1 - b0;
    if (nrows <= 0) return;

    __shared__ __hip_bfloat16 Bs[BN][LDB];  // TRANSPOSED [n][k], bf16

    // ---- stage + dequant B-slab ONCE: 512k x 64n codes ----
    // thread: fixed n, k-octets {ko + 32*i}, i = 0..15
    const int bn_ = tid & 63;
    const int ko  = (tid >> 6) * 8;   // 0,8,16,24 (wave-uniform)
    const int*    qcol  = qw + (size_t)e * IN * OUT + (size_t)kc * OUT + n0 + bn_;
    const float2* szcol = (const float2*)snz + (size_t)e * G * OUT + n0 + bn_;

#pragma unroll 4
    for (int i = 0; i < 16; ++i) {
        const int kb = ko + 32 * i;
        const int g  = (kc + kb) >> 6;
        const float2 sz = szcol[(size_t)g * OUT];
        const float s = sz.x;
        const float c = sz.y - 8.0f * s;          // (q-8)*s+z == q*s+c
        const int* qp = qcol + (size_t)kb * OUT;  // lanes n-contig -> coalesced
        int q[8];
#pragma unroll
        for (int j = 0; j < 8; ++j)
            q[j] = qp[(size_t)j * OUT];
        union { short8 v; __hip_bfloat162 h2[4]; } pb;
#pragma unroll
        for (int j = 0; j < 4; ++j) {
            const float f0 = (float)q[2 * j]     * s + c;
            const float f1 = (float)q[2 * j + 1] * s + c;
            pb.h2[j] = __float22bfloat162_rn(float2{f0, f1});
        }
        *(short8*)&Bs[bn_][kb] = pb.v;            // ds_write_b128
    }

    __syncthreads();   // the ONLY barrier

    // ---- token loop: 32-row wave-tiles, wave-strided; no barriers ----
    const int lane = tid & 63;
    const int wid  = tid >> 6;
    const int lm = lane & 15;
    const int lk = (lane >> 4) * 8;
    const int lq = (lane >> 4) * 4;

    for (int mt = wid; mt * 32 < nrows; mt += 4) {
        const int r0 = b0 + mt * 32;

        // per-lane A row pointers (clamped; garbage rows never stored)
        const __hip_bfloat16* abase[2];
#pragma unroll
        for (int i = 0; i < 2; ++i) {
            const int row = r0 + i * 16 + lm;
            const int rr  = row < b1 ? row : (b1 - 1);
            abase[i] = xb + (size_t)rr * IN + kc + lk;
        }

        floatx4 acc[2][4];
#pragma unroll
        for (int i = 0; i < 2; ++i)
#pragma unroll
            for (int j = 0; j < 4; ++j)
                acc[i][j] = (floatx4){0.f, 0.f, 0.f, 0.f};

#pragma unroll 4
        for (int ks = 0; ks < KC; ks += 32) {
            short8 af[2], bfr[4];
#pragma unroll
            for (int i = 0; i < 2; ++i)
                af[i] = *(const short8*)(abase[i] + ks);
#pragma unroll
            for (int j = 0; j < 4; ++j)
                bfr[j] = *(const short8*)&Bs[j * 16 + lm][ks + lk];
#pragma unroll
            for (int i = 0; i < 2; ++i)
#pragma unroll
                for (int j = 0; j < 4; ++j)
                    acc[i][j] = __builtin_amdgcn_mfma_f32_16x16x32_bf16(
                        af[i], bfr[j], acc[i][j], 0, 0, 0);
        }

        // epilogue: C/D layout col=lane&15, row=(lane>>4)*4+reg
#pragma unroll
        for (int i = 0; i < 2; ++i) {
#pragma unroll
            for (int r = 0; r < 4; ++r) {
                const int row = r0 + i * 16 + lq + r;
                if (row < b1) {
                    float* op = out + (size_t)row * OUT + n0 + lm;
#pragma unroll
                    for (int j = 0; j < 4; ++j)
                        atomicAdd(op + j * 16, acc[i][j][r]);
                }
            }
        }
    }
}

extern "C" void kernel_launch(void* const* d_in, const int* in_sizes, int n_in,
                              void* d_out, int out_size, void* d_ws, size_t ws_size,
                              hipStream_t stream) {
    const float* x   = (const float*)d_in[0];
    const int*   qw  = (const int*)d_in[1];
    const float* snz = (const float*)d_in[2];
    const int*   tpe = (const int*)d_in[3];
    float* out = (float*)d_out;
    __hip_bfloat16* xb = (__hip_bfloat16*)d_ws;   // T*IN*2 = 8.4 MB of ws

    // out poisoned 0xAA; k-split accumulates via atomics into zeroed out
    hipMemsetAsync(out, 0, (size_t)out_size * sizeof(float), stream);

    cvt_x_bf16<<<(T * IN) / (256 * 4), 256, 0, stream>>>(x, xb);

    dim3 grid(OUT / BN, KSPLIT, NE);   // 32 x 4 x 8 = 1024 blocks, all working
    hqq_grouped_gemm<<<grid, 256, 0, stream>>>(xb, qw, snz, tpe, out);
}